// Round 15
// baseline (38.695 us; speedup 1.0000x reference)
//
#include <hip/hip_runtime.h>

// HierarchicalMultinomialRegression: channel-parallel fused kernel, round 15.
// = round 11 (35.9us, best) with the 49-element M hoist moved off the LDS
// pipe onto the scalar-memory path.
//
// r11 pipe model: per-CU LDS unit ~54% busy (49 ds_read_b32 mm-hoist +
// 16 ds_read_b128 beta + shfl, ~476cy/wave x 98 waves/CU) = largest
// serialized resource. r12's cut failed because its replacement (49
// serialized v_readlane + extra global loads) cost more than the ds_reads.
// Cheap replacement: M is GLOBALLY uniform -> tiny pre-kernel computes
// M[49] into d_ws; main kernel reads it with wave-uniform constant-index
// loads -> compiler emits s_load (SMEM pipe, SGPR-resident, ~4 instrs,
// zero LDS / zero VALU). s_M staging + 49 ds_read + 49 readfirstlane
// deleted. Everything else r11-verbatim (both r13/r14 load restructures
// regressed; gather latency is already TLP-hidden).
// No launch_bounds min-waves cap (spill lessons r2/r6/r7).
//
// Math (verified r11): u_t[j] = rho_j^t sd_j e0[j] + sum_s rho_j^{t-s} nz_s[j],
// nz_s[j] = sum_k eps_s[k] M[k][j]; lane p owns steps {p+1,p+9,p+17};
// forward fold with rho^8 gaps; residual scale rho^{(t-p-1)&7};
// 21-shfl_xor butterfly; static cndmask select.
//
// Inputs: 0:X(N,64) 1:beta(64,7) 2:raw_rho(7,7) 3:raw_chol(7,7,7)
//         4:eps(B,7,20,7) 5:batter_ids 6:league_ids 7:season_ids
// Output: logits (N,8) then eps_sample (N,7), concat flat, f32.

#define NF 64
#define LDIM 7
#define TDIM 20
#define KM1 7
#define BLOCK 256
#define RPB (BLOCK / 8)   // rows per block = 32
#define BPAD 68           // betaT row stride (floats)

// ---- pre-kernel: M[k][j] = sum_i chol[k][i][j]  -> ws[k*7+j] ----
__global__ __launch_bounds__(64) void hmr_precompute(
    const float* __restrict__ raw_chol, float* __restrict__ ws)
{
    const int q = threadIdx.x;
    if (q < KM1 * KM1) {
        const int k = q / KM1, j = q - k * KM1;
        float m = 0.f;
        #pragma unroll
        for (int i = 0; i < LDIM; ++i)
            m += raw_chol[k * 49 + i * 7 + j];
        ws[q] = m;
    }
}

__global__ __launch_bounds__(BLOCK) void hmr_kernel(
    const float* __restrict__ X,
    const float* __restrict__ beta,
    const float* __restrict__ raw_rho,
    const float* __restrict__ raw_chol,
    const float* __restrict__ eps,
    const int* __restrict__ batter_ids,
    const int* __restrict__ league_ids,
    const int* __restrict__ season_ids,
    const float* __restrict__ Mws,     // precomputed M, wave-uniform
    float* __restrict__ out,
    int n_total)
{
    __shared__ __align__(16) float s_betaT[8][BPAD];  // betaT[k][j] = beta[j][k]
    __shared__ float s_rho[LDIM * 8];    // rho[l][k]
    __shared__ float s_sd[LDIM * 8];     // sd[l][k]

    const int tid = threadIdx.x;

    for (int i = tid; i < NF * KM1; i += BLOCK) {
        const int j = i / KM1, k = i - j * KM1;
        s_betaT[k][j] = beta[i];
    }
    if (tid < 64) {
        const int a = tid >> 3, c = tid & 7;
        if (a < LDIM) {
            float r = 0.f, sdv = 0.f;
            if (c < KM1) {
                r = tanhf(raw_rho[a * KM1 + c]);
                sdv = (1.0f / sqrtf(1.0f - r * r)) * raw_chol[c * 49 + a * 7 + a];
            }
            s_rho[a * 8 + c] = r;
            s_sd[a * 8 + c] = sdv;
        }
    }
    __syncthreads();

    const int r = tid >> 3;          // row within block
    const int p = tid & 7;           // lane-in-group: channel & step owner
    const int k_ld = (p < 6) ? p : 6;
    int n = blockIdx.x * RPB + r;
    const bool valid = (n < n_total);
    if (!valid) n = n_total - 1;

    const int b = batter_ids[n];
    const int l = league_ids[n];
    const int t = season_ids[n];

    // ---- fixed effects: acc = sum_j X[n,j] * beta[j, p] ----
    float acc = 0.f;
    {
        const float4* __restrict__ xrow =
            reinterpret_cast<const float4*>(X + (long)n * NF);
        const float4* __restrict__ brow =
            reinterpret_cast<const float4*>(&s_betaT[k_ld][0]);
        #pragma unroll 4
        for (int j4 = 0; j4 < NF / 4; ++j4) {
            const float4 x = xrow[j4];
            const float4 bb = brow[j4];
            acc = fmaf(x.x, bb.x, fmaf(x.y, bb.y,
                  fmaf(x.z, bb.z, fmaf(x.w, bb.w, acc))));
        }
    }

    // ---- M: wave-uniform constant-index loads -> scalar (SMEM) path ----
    float mm[KM1 * KM1];
    #pragma unroll
    for (int q2 = 0; q2 < KM1 * KM1; ++q2) mm[q2] = Mws[q2];

    // ---- per-group rho vector + rho^8 ----
    float rho_all[KM1], r8[KM1];
    #pragma unroll
    for (int j = 0; j < KM1; ++j) {
        rho_all[j] = s_rho[l * 8 + j];
        const float r2 = rho_all[j] * rho_all[j];
        const float r4 = r2 * r2;
        r8[j] = r4 * r4;
    }

    const float* __restrict__ erow = eps + ((long)b * LDIM + l) * (TDIM * KM1);

    // ---- owned steps s = p+1+8i, FORWARD fold (earliest first) ----
    float q[KM1];
    #pragma unroll
    for (int j = 0; j < KM1; ++j) q[j] = 0.f;

    #pragma unroll
    for (int i = 0; i < 3; ++i) {
        const int s = p + 1 + 8 * i;
        if (s <= t) {                      // exec-masked loads, r11-style
            float e[KM1];
            #pragma unroll
            for (int k = 0; k < KM1; ++k) e[k] = erow[s * KM1 + k];
            #pragma unroll
            for (int j = 0; j < KM1; ++j) {
                float nz = 0.f;
                #pragma unroll
                for (int k = 0; k < KM1; ++k)
                    nz = fmaf(e[k], mm[k * KM1 + j], nz);  // SGPR operand
                q[j] = fmaf(r8[j], q[j], nz);
            }
        }
    }

    // ---- scale by rho_j^((t-p-1)&7)  (q==0 when t<p+1, so &7 is safe) ----
    {
        const int m = (t - p - 1) & 7;
        float bs[KM1];
        #pragma unroll
        for (int j = 0; j < KM1; ++j) bs[j] = rho_all[j];
        #pragma unroll
        for (int bit = 0; bit < 3; ++bit) {
            const bool on = ((m >> bit) & 1) != 0;
            #pragma unroll
            for (int j = 0; j < KM1; ++j) {
                q[j] *= on ? bs[j] : 1.f;
                bs[j] *= bs[j];
            }
        }
    }

    // ---- butterfly-sum q over the 8-lane group ----
    #pragma unroll
    for (int j = 0; j < KM1; ++j) {
        q[j] += __shfl_xor(q[j], 1, 8);
        q[j] += __shfl_xor(q[j], 2, 8);
        q[j] += __shfl_xor(q[j], 4, 8);
    }
    // select own channel (static indices -> cndmask chain)
    float nzt = q[0];
    #pragma unroll
    for (int j = 1; j < KM1; ++j) nzt = (p == j) ? q[j] : nzt;

    // ---- e0 term: rho_own^t * sd * e0 ----
    const float e0 = erow[k_ld];
    const float sd = s_sd[l * 8 + k_ld];
    float rho_own = rho_all[0];
    #pragma unroll
    for (int j = 1; j < KM1; ++j) rho_own = (k_ld == j) ? rho_all[j] : rho_own;
    float pwt = 1.f;
    {
        float bo = rho_own;
        #pragma unroll
        for (int bit = 0; bit < 5; ++bit) {
            pwt *= (((t >> bit) & 1) != 0) ? bo : 1.f;
            bo *= bo;
        }
    }
    const float u = fmaf(pwt * sd, e0, nzt);
    const float last_e = erow[t * KM1 + k_ld];

    // ---- coalesced writes, no staging ----
    if (valid) {
        const int col = (p == 7) ? 0 : p + 1;
        out[(long)n * 8 + col] = (p == 7) ? 0.f : (acc + u);
        if (p < KM1)
            out[(long)n_total * 8 + (long)n * KM1 + p] = last_e;
    }
}

extern "C" void kernel_launch(void* const* d_in, const int* in_sizes, int n_in,
                              void* d_out, int out_size, void* d_ws, size_t ws_size,
                              hipStream_t stream)
{
    const float* X        = (const float*)d_in[0];
    const float* beta     = (const float*)d_in[1];
    const float* raw_rho  = (const float*)d_in[2];
    const float* raw_chol = (const float*)d_in[3];
    const float* eps      = (const float*)d_in[4];
    const int* batter_ids = (const int*)d_in[5];
    const int* league_ids = (const int*)d_in[6];
    const int* season_ids = (const int*)d_in[7];
    float* out = (float*)d_out;
    float* ws  = (float*)d_ws;

    const int n_total = in_sizes[5];  // N = 200000
    const int grid = (n_total + RPB - 1) / RPB;

    hmr_precompute<<<1, 64, 0, stream>>>(raw_chol, ws);
    hmr_kernel<<<grid, BLOCK, 0, stream>>>(X, beta, raw_rho, raw_chol, eps,
                                           batter_ids, league_ids, season_ids,
                                           ws, out, n_total);
}

// Round 16
// 35.854 us; speedup vs baseline: 1.0792x; 1.0792x over previous
//
#include <hip/hip_runtime.h>

// HierarchicalMultinomialRegression: channel-parallel fused kernel.
// FINAL (= round 11, 35.9us, best of 15 rounds).
//
// Structure: one 8-lane group per row n; lane p owns output channel p and
// timesteps {p+1, p+9, p+17}. Never materializes u (B,L,T,Km1).
//   u_t[j] = rho_j^t sd_j e0[j] + sum_{s=1..t} rho_j^{t-s} nz_s[j],
//   nz_s[j] = sum_k eps_s[k] * M[k][j].
// Lane p loads each owned step's FULL 7-float eps row once (exec-masked
// if s<=t) -> each eps cacheline touched ~once (the key win: rounds 3/9
// step-serial loads re-touched lines ~10x -> L3 re-fetch wall at ~47us).
// M held in 49 SGPRs via readfirstlane of broadcast LDS reads; forward
// fold with rho^8 gaps; residual scale rho^{(t-p-1)&7} (bit-decomposed,
// exact for negative rho); 21-shfl_xor width-8 butterfly; static cndmask
// select; fully-coalesced unstaged writes.
//
// Experimentally falsified alternatives (kept for the record):
//  r12 readlane-M 38.2 / r13 unconditional loads 41.8 / r14 early
//  predicated loads 38.4 / r15 SMEM-M+prekernel 38.7 -- gather latency is
//  TLP-hidden at ~98 waves/CU; LDS pipe is not binding. Remaining gap to
//  the ~21us streaming floor is random line-granularity eps gather:
//  ~136MB effective traffic in 35.9us = 3.8 TB/s (~60% of streaming peak),
//  near-minimal line touches, no exploitable reuse.
// NEVER set launch_bounds min-waves (r2/r6/r7: spill catastrophes).
//
// Inputs: 0:X(N,64) 1:beta(64,7) 2:raw_rho(7,7) 3:raw_chol(7,7,7)
//         4:eps(B,7,20,7) 5:batter_ids 6:league_ids 7:season_ids
// Output: logits (N,8) then eps_sample (N,7), concat flat, f32.

#define NF 64
#define LDIM 7
#define TDIM 20
#define KM1 7
#define BLOCK 256
#define RPB (BLOCK / 8)   // rows per block = 32
#define BPAD 68           // betaT row stride (floats)

__device__ __forceinline__ float rfl(float x) {
    return __int_as_float(__builtin_amdgcn_readfirstlane(__float_as_int(x)));
}

__global__ __launch_bounds__(BLOCK) void hmr_kernel(
    const float* __restrict__ X,
    const float* __restrict__ beta,
    const float* __restrict__ raw_rho,
    const float* __restrict__ raw_chol,
    const float* __restrict__ eps,
    const int* __restrict__ batter_ids,
    const int* __restrict__ league_ids,
    const int* __restrict__ season_ids,
    float* __restrict__ out,
    int n_total)
{
    __shared__ __align__(16) float s_betaT[8][BPAD];  // betaT[k][j] = beta[j][k]
    __shared__ float s_rho[LDIM * 8];    // rho[l][k]
    __shared__ float s_sd[LDIM * 8];     // sd[l][k]
    __shared__ float s_M[64];            // M[k][j] stride 8, padded zero

    const int tid = threadIdx.x;

    for (int i = tid; i < NF * KM1; i += BLOCK) {
        const int j = i / KM1, k = i - j * KM1;
        s_betaT[k][j] = beta[i];
    }
    if (tid < 64) {
        const int a = tid >> 3, c = tid & 7;
        float m = 0.f;
        if (a < KM1 && c < KM1) {
            #pragma unroll
            for (int i2 = 0; i2 < LDIM; ++i2)
                m += raw_chol[a * 49 + i2 * 7 + c];   // M[k=a][j=c]
        }
        s_M[tid] = m;
        if (a < LDIM) {
            float r = 0.f, sdv = 0.f;
            if (c < KM1) {
                r = tanhf(raw_rho[a * KM1 + c]);
                sdv = (1.0f / sqrtf(1.0f - r * r)) * raw_chol[c * 49 + a * 7 + a];
            }
            s_rho[a * 8 + c] = r;
            s_sd[a * 8 + c] = sdv;
        }
    }
    __syncthreads();

    const int r = tid >> 3;          // row within block
    const int p = tid & 7;           // lane-in-group: channel & step owner
    const int k_ld = (p < 6) ? p : 6;
    int n = blockIdx.x * RPB + r;
    const bool valid = (n < n_total);
    if (!valid) n = n_total - 1;

    const int b = batter_ids[n];
    const int l = league_ids[n];
    const int t = season_ids[n];

    // ---- fixed effects: acc = sum_j X[n,j] * beta[j, p] ----
    float acc = 0.f;
    {
        const float4* __restrict__ xrow =
            reinterpret_cast<const float4*>(X + (long)n * NF);
        const float4* __restrict__ brow =
            reinterpret_cast<const float4*>(&s_betaT[k_ld][0]);
        #pragma unroll 4
        for (int j4 = 0; j4 < NF / 4; ++j4) {
            const float4 x = xrow[j4];
            const float4 bb = brow[j4];
            acc = fmaf(x.x, bb.x, fmaf(x.y, bb.y,
                  fmaf(x.z, bb.z, fmaf(x.w, bb.w, acc))));
        }
    }

    // ---- hoist wave-uniform M into SGPRs ----
    float mm[KM1 * KM1];
    #pragma unroll
    for (int k = 0; k < KM1; ++k)
        #pragma unroll
        for (int j = 0; j < KM1; ++j)
            mm[k * KM1 + j] = rfl(s_M[k * 8 + j]);

    // ---- per-group rho vector + rho^8 ----
    float rho_all[KM1], r8[KM1];
    #pragma unroll
    for (int j = 0; j < KM1; ++j) {
        rho_all[j] = s_rho[l * 8 + j];
        const float r2 = rho_all[j] * rho_all[j];
        const float r4 = r2 * r2;
        r8[j] = r4 * r4;
    }

    const float* __restrict__ erow = eps + ((long)b * LDIM + l) * (TDIM * KM1);

    // ---- owned steps s = p+1+8i, FORWARD fold (earliest first) ----
    // nz at owned step i carries r8^{imax-i}; residual scale applied below.
    float q[KM1];
    #pragma unroll
    for (int j = 0; j < KM1; ++j) q[j] = 0.f;

    #pragma unroll
    for (int i = 0; i < 3; ++i) {
        const int s = p + 1 + 8 * i;
        if (s <= t) {                      // t<=19 so s<TDIM guaranteed
            float e[KM1];
            #pragma unroll
            for (int k = 0; k < KM1; ++k) e[k] = erow[s * KM1 + k];
            #pragma unroll
            for (int j = 0; j < KM1; ++j) {
                float nz = 0.f;
                #pragma unroll
                for (int k = 0; k < KM1; ++k)
                    nz = fmaf(e[k], mm[k * KM1 + j], nz);  // SGPR operand
                q[j] = fmaf(r8[j], q[j], nz);
            }
        }
    }

    // ---- scale by rho_j^((t-p-1)&7)  (q==0 when t<p+1, so &7 is safe) ----
    {
        const int m = (t - p - 1) & 7;
        float bs[KM1];
        #pragma unroll
        for (int j = 0; j < KM1; ++j) bs[j] = rho_all[j];
        #pragma unroll
        for (int bit = 0; bit < 3; ++bit) {
            const bool on = ((m >> bit) & 1) != 0;
            #pragma unroll
            for (int j = 0; j < KM1; ++j) {
                q[j] *= on ? bs[j] : 1.f;
                bs[j] *= bs[j];
            }
        }
    }

    // ---- butterfly-sum q over the 8-lane group ----
    #pragma unroll
    for (int j = 0; j < KM1; ++j) {
        q[j] += __shfl_xor(q[j], 1, 8);
        q[j] += __shfl_xor(q[j], 2, 8);
        q[j] += __shfl_xor(q[j], 4, 8);
    }
    // select own channel (static indices -> cndmask chain)
    float nzt = q[0];
    #pragma unroll
    for (int j = 1; j < KM1; ++j) nzt = (p == j) ? q[j] : nzt;

    // ---- e0 term: rho_own^t * sd * e0 ----
    const float e0 = erow[k_ld];
    const float sd = s_sd[l * 8 + k_ld];
    float rho_own = rho_all[0];
    #pragma unroll
    for (int j = 1; j < KM1; ++j) rho_own = (k_ld == j) ? rho_all[j] : rho_own;
    float pwt = 1.f;
    {
        float bo = rho_own;
        #pragma unroll
        for (int bit = 0; bit < 5; ++bit) {
            pwt *= (((t >> bit) & 1) != 0) ? bo : 1.f;
            bo *= bo;
        }
    }
    const float u = fmaf(pwt * sd, e0, nzt);
    const float last_e = erow[t * KM1 + k_ld];

    // ---- coalesced writes, no staging ----
    if (valid) {
        const int col = (p == 7) ? 0 : p + 1;
        out[(long)n * 8 + col] = (p == 7) ? 0.f : (acc + u);
        if (p < KM1)
            out[(long)n_total * 8 + (long)n * KM1 + p] = last_e;
    }
}

extern "C" void kernel_launch(void* const* d_in, const int* in_sizes, int n_in,
                              void* d_out, int out_size, void* d_ws, size_t ws_size,
                              hipStream_t stream)
{
    const float* X        = (const float*)d_in[0];
    const float* beta     = (const float*)d_in[1];
    const float* raw_rho  = (const float*)d_in[2];
    const float* raw_chol = (const float*)d_in[3];
    const float* eps      = (const float*)d_in[4];
    const int* batter_ids = (const int*)d_in[5];
    const int* league_ids = (const int*)d_in[6];
    const int* season_ids = (const int*)d_in[7];
    float* out = (float*)d_out;

    const int n_total = in_sizes[5];  // N = 200000
    const int grid = (n_total + RPB - 1) / RPB;

    hmr_kernel<<<grid, BLOCK, 0, stream>>>(X, beta, raw_rho, raw_chol, eps,
                                           batter_ids, league_ids, season_ids,
                                           out, n_total);
}